// Round 15
// baseline (74.782 us; speedup 1.0000x reference)
//
#include <hip/hip_runtime.h>
#include <hip/hip_fp16.h>

#define NPIX 16384

typedef __attribute__((ext_vector_type(8))) short short8;
typedef __attribute__((ext_vector_type(8))) _Float16 half8;
typedef __attribute__((ext_vector_type(4))) float f32x4;

__device__ __forceinline__ unsigned short f2bf(float f) {
    unsigned u = __float_as_uint(f);
    unsigned r = (u + 0x7fffu + ((u >> 16) & 1u)) >> 16;
    return (unsigned short)r;
}
__device__ __forceinline__ unsigned short f2h_us(float f) {
    union { _Float16 h; unsigned short u; } cv;
    cv.h = (_Float16)f;
    return cv.u;
}
__device__ __forceinline__ unsigned hdup(float f) {
    unsigned short u = f2h_us(f);
    return (unsigned)u | ((unsigned)u << 16);
}
__device__ __forceinline__ unsigned hfma2u(unsigned w, unsigned v, unsigned a) {
    union { unsigned u; __half2 h; } W, V, A, R;
    W.u = w; V.u = v; A.u = a;
    R.h = __hfma2(W.h, V.h, A.h);
    return R.u;
}
__device__ __forceinline__ unsigned hadd2u(unsigned a, unsigned b) {
    union { unsigned u; __half2 h; } A, B, R;
    A.u = a; B.u = b;
    R.h = __hadd2(A.h, B.h);
    return R.u;
}

#define GLOAD16(SRC, DST) \
    __builtin_amdgcn_global_load_lds( \
        (const __attribute__((address_space(1))) unsigned*)(SRC), \
        (__attribute__((address_space(3))) unsigned*)(DST), 16, 0, 0)

// ---------------------------------------------------------------------------
// prep_all: blocks 0..2047 x->bf16 (XCD-aligned); 2048..2099 Wt transpose;
// 2100 biasD+pad. Wt n-rows: 0-255 v_w | 256-399 qd_w | 400-471 qs_w |
// 472-543 qw_w | 544-575 zero | 576-831 out_w (f16; rest bf16).
// ---------------------------------------------------------------------------
__device__ __forceinline__ float wsrc(int k, int n,
    const float* v_w, const float* qd_w, const float* qs_w,
    const float* qw_w, const float* out_w)
{
    if (n < 256) return v_w[k * 256 + n];
    n -= 256;
    if (n < 144) return qd_w[k * 144 + n];
    n -= 144;
    if (n < 72)  return qs_w[k * 72 + n];
    n -= 72;
    if (n < 72)  return qw_w[k * 72 + n];
    n -= 72;
    if (n < 32)  return 0.f;
    return out_w[k * 256 + (n - 32)];
}

__global__ __launch_bounds__(256) void prep_all(
    const float* __restrict__ x, unsigned short* __restrict__ xb,
    const float* __restrict__ v_w, const float* __restrict__ qd_w,
    const float* __restrict__ qs_w, const float* __restrict__ qw_w,
    const float* __restrict__ out_w, const float* __restrict__ qd_b,
    const float* __restrict__ qw_b,
    unsigned short* __restrict__ Wt, float* __restrict__ biasD,
    unsigned short* __restrict__ vpad)
{
    __shared__ float t[64][65];
    const int bid = blockIdx.x;
    const int tid = threadIdx.x;

    if (bid < 2048) {
        const int bb = (bid >> 3) + (bid & 7) * 256;
        const size_t i = (size_t)bb * 256 + tid;
        const float4 v0 = *(const float4*)(x + i * 8);
        const float4 v1 = *(const float4*)(x + i * 8 + 4);
        uint4 pk;
        pk.x = f2bf(v0.x) | ((unsigned)f2bf(v0.y) << 16);
        pk.y = f2bf(v0.z) | ((unsigned)f2bf(v0.w) << 16);
        pk.z = f2bf(v1.x) | ((unsigned)f2bf(v1.y) << 16);
        pk.w = f2bf(v1.z) | ((unsigned)f2bf(v1.w) << 16);
        *(uint4*)(xb + i * 8) = pk;
        return;
    }
    if (bid == 2100) {
        for (int i = tid; i < 320; i += 256) {
            float bv = 0.f;
            if (i < 144)                  bv = qd_b[i];
            else if (i >= 216 && i < 288) bv = qw_b[i - 216];
            biasD[i] = bv;
        }
        for (int i = tid; i < 512; i += 256) vpad[i] = 0;
        return;
    }
    const int tile = bid - 2048;
    const int tn = tile % 13;
    const int tk = tile / 13;
    #pragma unroll
    for (int i = 0; i < 16; ++i) {
        const int idx = tid + i * 256;
        const int r = idx >> 6;
        const int c = idx & 63;
        t[r][c] = wsrc(tk * 64 + r, tn * 64 + c, v_w, qd_w, qs_w, qw_w, out_w);
    }
    __syncthreads();
    const bool asF16 = (tn >= 9);
    #pragma unroll
    for (int i = 0; i < 8; ++i) {
        const int idx = tid + i * 256;
        const int rn = idx >> 5;
        const int cc = idx & 31;
        unsigned pk;
        if (asF16)
            pk = (unsigned)f2h_us(t[cc * 2][rn]) | ((unsigned)f2h_us(t[cc * 2 + 1][rn]) << 16);
        else
            pk = (unsigned)f2bf(t[cc * 2][rn]) | ((unsigned)f2bf(t[cc * 2 + 1][rn]) << 16);
        ((unsigned*)(Wt + (size_t)(tn * 64 + rn) * 256 + tk * 64))[cc] = pk;
    }
}

// ---------------------------------------------------------------------------
// gemm_proj: [NPIX][256]bf16 @ Wt[j*64..][256]^T, j=0..8. XCD-remapped rows.
//   j<4  -> v_bf F16 GROUP-MAJOR [b][g][4096][32];  j>=4 -> proj f32 [NPIX][320]
// ---------------------------------------------------------------------------
__global__ __launch_bounds__(256) void gemm_proj(
    const unsigned short* __restrict__ A, const unsigned short* __restrict__ Wt,
    const float* __restrict__ v_b, const float* __restrict__ biasD,
    unsigned short* __restrict__ v_bf, float* __restrict__ proj)
{
    __shared__ unsigned short As[64 * 256];
    __shared__ unsigned short Bs[64 * 256];

    const int tid  = threadIdx.x;
    const int wid  = tid >> 6;
    const int lane = tid & 63;
    const int bx   = blockIdx.x;
    const int tile = (bx >> 3) + (bx & 7) * 32;
    const int row0 = tile * 64;
    const int j    = blockIdx.y;

    const unsigned short* Ab = A  + (size_t)row0 * 256;
    const unsigned short* Bb = Wt + (size_t)(j * 64) * 256;
    const int rl = lane >> 5;
    const int gl = lane & 31;

    #pragma unroll
    for (int it = 0; it < 8; ++it) {
        const int r   = wid * 16 + it * 2 + rl;
        const int gsw = gl ^ (r & 7);
        GLOAD16(Ab + r * 256 + gsw * 8, &As[(wid * 16 + it * 2) * 256]);
        GLOAD16(Bb + r * 256 + gsw * 8, &Bs[(wid * 16 + it * 2) * 256]);
    }
    asm volatile("s_waitcnt vmcnt(0)" ::: "memory");
    __syncthreads();

    f32x4 acc00 = {0,0,0,0}, acc01 = {0,0,0,0};
    f32x4 acc10 = {0,0,0,0}, acc11 = {0,0,0,0};

    const int wr = (wid >> 1) * 32;
    const int wc = (wid & 1) * 32;
    const int fr = lane & 15;
    const int fg = lane >> 4;

    const int ra0 = wr + fr, ra1 = ra0 + 16;
    const int rb0 = wc + fr, rb1 = rb0 + 16;
    const int sa  = ra0 & 7;
    const int sb  = rb0 & 7;

    #pragma unroll
    for (int t = 0; t < 8; ++t) {
        const int gran = t * 4 + fg;
        short8 a0 = *(const short8*)&As[ra0 * 256 + (gran ^ sa) * 8];
        short8 a1 = *(const short8*)&As[ra1 * 256 + (gran ^ sa) * 8];
        short8 b0 = *(const short8*)&Bs[rb0 * 256 + (gran ^ sb) * 8];
        short8 b1 = *(const short8*)&Bs[rb1 * 256 + (gran ^ sb) * 8];
        acc00 = __builtin_amdgcn_mfma_f32_16x16x32_bf16(a0, b0, acc00, 0, 0, 0);
        acc01 = __builtin_amdgcn_mfma_f32_16x16x32_bf16(a0, b1, acc01, 0, 0, 0);
        acc10 = __builtin_amdgcn_mfma_f32_16x16x32_bf16(a1, b0, acc10, 0, 0, 0);
        acc11 = __builtin_amdgcn_mfma_f32_16x16x32_bf16(a1, b1, acc11, 0, 0, 0);
    }

    if (j < 4) {
        const int colA = j * 64 + wc + fr;
        const int colB = colA + 16;
        const int gA = colA >> 5, cA = colA & 31;
        const int gB = colB >> 5, cB = colB & 31;
        const float biasA = v_b[colA];
        const float biasB = v_b[colB];
        #pragma unroll
        for (int jj = 0; jj < 4; ++jj) {
            const int r0a = row0 + wr + fg * 4 + jj;
            const int r1a = r0a + 16;
            const int b0i = r0a >> 12;
            const int hw0 = r0a & 4095, hw1 = r1a & 4095;
            v_bf[((size_t)(b0i * 8 + gA) * 4096 + hw0) * 32 + cA] = f2h_us(acc00[jj] + biasA);
            v_bf[((size_t)(b0i * 8 + gB) * 4096 + hw0) * 32 + cB] = f2h_us(acc01[jj] + biasB);
            v_bf[((size_t)(b0i * 8 + gA) * 4096 + hw1) * 32 + cA] = f2h_us(acc10[jj] + biasA);
            v_bf[((size_t)(b0i * 8 + gB) * 4096 + hw1) * 32 + cB] = f2h_us(acc11[jj] + biasB);
        }
    } else {
        const int colA = (j - 4) * 64 + wc + fr;
        const int colB = colA + 16;
        const float biasA = biasD[colA];
        const float biasB = biasD[colB];
        #pragma unroll
        for (int jj = 0; jj < 4; ++jj) {
            const int r0a = row0 + wr + fg * 4 + jj;
            const int r1a = r0a + 16;
            proj[(size_t)r0a * 320 + colA] = acc00[jj] + biasA;
            proj[(size_t)r0a * 320 + colB] = acc01[jj] + biasB;
            proj[(size_t)r1a * 320 + colA] = acc10[jj] + biasA;
            proj[(size_t)r1a * 320 + colB] = acc11[jj] + biasB;
        }
    }
}

// ---------------------------------------------------------------------------
// dcn_fused: sampler (v7) + output GEMM fused. One block = 8 pixels.
// Phase 1: offs/wpk; Phase 2: packed-f16 gathers -> mid tile in LDS
// (16 rows x stride 264 f16; rows 8-15 zero-padded, pad kills bank
// conflicts on ds_read_b128). Phase 3: mini-MFMA GEMM
// out[8][256] = mid_s @ WtO^T + out_b, B-fragments direct from L2-hot Wt.
// Fragment mapping identical to the proven gemm_out (A: row=fr,k=t*32+fg*8;
// D: col=fr,row=fg*4+jj).
// ---------------------------------------------------------------------------
__global__ __launch_bounds__(256) void dcn_fused(
    const unsigned short* __restrict__ vbuf,  // [4][8][4096][32] f16
    const float* __restrict__ proj,           // [NPIX][320]
    const float* __restrict__ prior,          // [K][2]
    const float* __restrict__ dscale,         // [G]
    const unsigned short* __restrict__ WtO,   // [256][256] f16  [n][k]
    const float* __restrict__ out_b,          // [256]
    float* __restrict__ out)                  // [NPIX][256] f32
{
    __shared__ int      offs[576 * 2];           //  4608 B
    __shared__ unsigned wpk [576 * 4];           //  9216 B
    __shared__ unsigned short mid_s[16 * 264];   //  8448 B  (stride 264 = pad)

    const int tid = threadIdx.x;
    const int bid  = blockIdx.x;
    const int wg   = (bid & 7) * 256 + (bid >> 3);
    const int pix0 = wg * 8;

    // zero mid_s (rows 8-15 must be zero for the M=16 MFMA; rows 0-7 get
    // fully overwritten). 16*264*2B = 8448B = 528 uint4.
    for (int i = tid; i < 528; i += 256) ((uint4*)mid_s)[i] = make_uint4(0,0,0,0);

    for (int it = tid; it < 576; it += 256) {
        const int p   = it / 72;
        const int rem = it - p * 72;
        const int g   = rem / 9;
        const int k   = rem - g * 9;
        const int pix = pix0 + p;
        const int b   = pix >> 12;
        const int hw  = pix & 4095;
        const int h   = hw >> 6, w = hw & 63;

        const float* row = proj + (size_t)pix * 320;
        const float qdx = row[g * 18 + k * 2 + 0];
        const float qdy = row[g * 18 + k * 2 + 1];
        const float s   = row[144 + g * 9 + k] + dscale[g];
        const float wt  = row[216 + g * 9 + k];
        const float sig6 = 6.0f / (1.0f + __expf(-s));
        const float px = (float)w + (qdx + prior[k * 2 + 0]) * sig6;
        const float py = (float)h + (qdy + prior[k * 2 + 1]) * sig6;

        const float x0f = floorf(px), y0f = floorf(py);
        const int ix = (int)x0f, iy = (int)y0f;
        const float wx1 = px - x0f, wx0 = 1.f - wx1;
        const float wy1 = py - y0f, wy0 = 1.f - wy1;
        const int plane = (b * 8 + g) << 12;

        const bool vy0 = (iy >= 0) & (iy < 64);
        const bool vy1 = (iy >= -1) & (iy < 63);
        const bool vx0 = (ix >= 0) & (ix < 64);
        const bool vx1 = (ix >= -1) & (ix < 63);
        const float w00 = (vy0 & vx0) ? wt * wy0 * wx0 : 0.f;
        const float w10 = (vy1 & vx0) ? wt * wy1 * wx0 : 0.f;
        const float w01 = (vy0 & vx1) ? wt * wy0 * wx1 : 0.f;
        const float w11 = (vy1 & vx1) ? wt * wy1 * wx1 : 0.f;
        wpk[it * 4 + 0] = hdup(w00);
        wpk[it * 4 + 1] = hdup(w10);
        wpk[it * 4 + 2] = hdup(w01);
        wpk[it * 4 + 3] = hdup(w11);

        const int xs  = min(max(ix,     -1), 63);
        const int y0c = min(max(iy,      0), 63);
        const int y1c = min(max(iy + 1,  0), 63);
        offs[it * 2 + 0] = (plane + y0c * 64 + xs) * 64;   // BYTE offsets
        offs[it * 2 + 1] = (plane + y1c * 64 + xs) * 64;
    }
    __syncthreads();

    {
        const int p4 = tid >> 6;
        const int g  = (tid >> 3) & 7;
        const int q  = tid & 7;
        const int xh = q >> 2;
        const int qb = q * 16;
        const char* vbb = (const char*)vbuf;

        unsigned aA0=0,aA1=0,aA2=0,aA3=0, aB0=0,aB1=0,aB2=0,aB3=0;
        unsigned bA0=0,bA1=0,bA2=0,bA3=0, bB0=0,bB1=0,bB2=0,bB3=0;
        const int item0a = p4 * 72 + g * 9;
        const int item0b = (p4 + 4) * 72 + g * 9;

        #pragma unroll
        for (int k = 0; k < 9; ++k) {
            {
                const int it = item0a + k;
                const int2  o2 = *(const int2*)&offs[it * 2];
                const uint2 wp = *(const uint2*)&wpk[it * 4 + xh * 2];
                const uint4 r0 = *(const uint4*)(vbb + o2.x + qb);
                const uint4 r1 = *(const uint4*)(vbb + o2.y + qb);
                aA0 = hfma2u(wp.x, r0.x, aA0);
                aA1 = hfma2u(wp.x, r0.y, aA1);
                aA2 = hfma2u(wp.x, r0.z, aA2);
                aA3 = hfma2u(wp.x, r0.w, aA3);
                aB0 = hfma2u(wp.y, r1.x, aB0);
                aB1 = hfma2u(wp.y, r1.y, aB1);
                aB2 = hfma2u(wp.y, r1.z, aB2);
                aB3 = hfma2u(wp.y, r1.w, aB3);
            }
            {
                const int it = item0b + k;
                const int2  o2 = *(const int2*)&offs[it * 2];
                const uint2 wp = *(const uint2*)&wpk[it * 4 + xh * 2];
                const uint4 r0 = *(const uint4*)(vbb + o2.x + qb);
                const uint4 r1 = *(const uint4*)(vbb + o2.y + qb);
                bA0 = hfma2u(wp.x, r0.x, bA0);
                bA1 = hfma2u(wp.x, r0.y, bA1);
                bA2 = hfma2u(wp.x, r0.z, bA2);
                bA3 = hfma2u(wp.x, r0.w, bA3);
                bB0 = hfma2u(wp.y, r1.x, bB0);
                bB1 = hfma2u(wp.y, r1.y, bB1);
                bB2 = hfma2u(wp.y, r1.z, bB2);
                bB3 = hfma2u(wp.y, r1.w, bB3);
            }
        }

        uint4 oA, oB;
        {
            unsigned c;
            c = hadd2u(aA0, aB0); c = hadd2u(c, (unsigned)__shfl_xor((int)c, 4)); oA.x = c;
            c = hadd2u(aA1, aB1); c = hadd2u(c, (unsigned)__shfl_xor((int)c, 4)); oA.y = c;
            c = hadd2u(aA2, aB2); c = hadd2u(c, (unsigned)__shfl_xor((int)c, 4)); oA.z = c;
            c = hadd2u(aA3, aB3); c = hadd2u(c, (unsigned)__shfl_xor((int)c, 4)); oA.w = c;
            c = hadd2u(bA0, bB0); c = hadd2u(c, (unsigned)__shfl_xor((int)c, 4)); oB.x = c;
            c = hadd2u(bA1, bB1); c = hadd2u(c, (unsigned)__shfl_xor((int)c, 4)); oB.y = c;
            c = hadd2u(bA2, bB2); c = hadd2u(c, (unsigned)__shfl_xor((int)c, 4)); oB.z = c;
            c = hadd2u(bA3, bB3); c = hadd2u(c, (unsigned)__shfl_xor((int)c, 4)); oB.w = c;
        }
        if (xh == 0) {
            const int cq8 = (q & 3) * 8;
            *(uint4*)&mid_s[(p4    ) * 264 + g * 32 + cq8] = oA;
            *(uint4*)&mid_s[(p4 + 4) * 264 + g * 32 + cq8] = oB;
        }
    }
    __syncthreads();

    // ---------------- Phase 3: out[8][256] = mid_s @ WtO^T + out_b --------
    {
        const int wv = tid >> 6;        // wave 0..3 -> cols wv*64..+63
        const int ln = tid & 63;
        const int fr = ln & 15;
        const int fg = ln >> 4;
        const int col0 = wv * 64;

        f32x4 acc0 = {0,0,0,0}, acc1 = {0,0,0,0}, acc2 = {0,0,0,0}, acc3 = {0,0,0,0};

        #pragma unroll
        for (int t = 0; t < 8; ++t) {
            const half8 a = *(const half8*)&mid_s[fr * 264 + t * 32 + fg * 8];
            const half8 b0 = *(const half8*)(WtO + (size_t)(col0 + 0  + fr) * 256 + t * 32 + fg * 8);
            const half8 b1 = *(const half8*)(WtO + (size_t)(col0 + 16 + fr) * 256 + t * 32 + fg * 8);
            const half8 b2 = *(const half8*)(WtO + (size_t)(col0 + 32 + fr) * 256 + t * 32 + fg * 8);
            const half8 b3 = *(const half8*)(WtO + (size_t)(col0 + 48 + fr) * 256 + t * 32 + fg * 8);
            acc0 = __builtin_amdgcn_mfma_f32_16x16x32_f16(a, b0, acc0, 0, 0, 0);
            acc1 = __builtin_amdgcn_mfma_f32_16x16x32_f16(a, b1, acc1, 0, 0, 0);
            acc2 = __builtin_amdgcn_mfma_f32_16x16x32_f16(a, b2, acc2, 0, 0, 0);
            acc3 = __builtin_amdgcn_mfma_f32_16x16x32_f16(a, b3, acc3, 0, 0, 0);
        }

        // D: col = col0 + n*16 + fr, row = fg*4 + jj; only rows 0-7 valid
        if (fg < 2) {
            const float bias0 = out_b[col0 + 0  + fr];
            const float bias1 = out_b[col0 + 16 + fr];
            const float bias2 = out_b[col0 + 32 + fr];
            const float bias3 = out_b[col0 + 48 + fr];
            #pragma unroll
            for (int jj = 0; jj < 4; ++jj) {
                const int row = fg * 4 + jj;
                float* orow = out + (size_t)(pix0 + row) * 256 + col0;
                orow[0  + fr] = acc0[jj] + bias0;
                orow[16 + fr] = acc1[jj] + bias1;
                orow[32 + fr] = acc2[jj] + bias2;
                orow[48 + fr] = acc3[jj] + bias3;
            }
        }
    }
}

// ---------------------------------------------------------------------------
extern "C" void kernel_launch(void* const* d_in, const int* in_sizes, int n_in,
                              void* d_out, int out_size, void* d_ws, size_t ws_size,
                              hipStream_t stream)
{
    (void)in_sizes; (void)n_in; (void)out_size; (void)ws_size;

    const float* x      = (const float*)d_in[0];
    const float* v_w    = (const float*)d_in[1];
    const float* v_b    = (const float*)d_in[2];
    const float* qd_w   = (const float*)d_in[3];
    const float* qd_b   = (const float*)d_in[4];
    const float* qs_w   = (const float*)d_in[5];
    const float* qw_w   = (const float*)d_in[6];
    const float* qw_b   = (const float*)d_in[7];
    const float* out_w  = (const float*)d_in[8];
    const float* out_b  = (const float*)d_in[9];
    const float* prior  = (const float*)d_in[10];
    const float* dscale = (const float*)d_in[11];
    float* out = (float*)d_out;

    char* ws = (char*)d_ws;
    unsigned short* xb    = (unsigned short*)(ws);                    // 8 MB
    unsigned short* v_bf  = (unsigned short*)(ws + 8388608);          // 8 MB (f16)
    unsigned short* vpad  = (unsigned short*)(ws + 16777216);         // 1 KB guard
    float*          proj  = (float*)(ws + 16778240);                  // ~21 MB
    unsigned short* Wt    = (unsigned short*)(ws + 46138368);         // 416 KB
    float*          biasD = (float*)(ws + 46564352);                  // 1.25 KB

    prep_all<<<dim3(2101), dim3(256), 0, stream>>>(x, xb, v_w, qd_w, qs_w, qw_w,
                                                   out_w, qd_b, qw_b, Wt, biasD, vpad);

    gemm_proj<<<dim3(256, 9), dim3(256), 0, stream>>>(xb, Wt, v_b, biasD, v_bf, proj);

    dcn_fused<<<dim3(NPIX / 8), dim3(256), 0, stream>>>(v_bf, proj, prior, dscale,
                                                        Wt + 576 * 256, out_b, out);
}

// Round 16
// 55.912 us; speedup vs baseline: 1.3375x; 1.3375x over previous
//
#include <hip/hip_runtime.h>
#include <hip/hip_fp16.h>

#define NPIX 16384

typedef __attribute__((ext_vector_type(8))) short short8;
typedef __attribute__((ext_vector_type(8))) _Float16 half8;
typedef __attribute__((ext_vector_type(4))) float f32x4;

__device__ __forceinline__ unsigned short f2bf(float f) {
    unsigned u = __float_as_uint(f);
    unsigned r = (u + 0x7fffu + ((u >> 16) & 1u)) >> 16;
    return (unsigned short)r;
}
__device__ __forceinline__ unsigned short f2h_us(float f) {
    union { _Float16 h; unsigned short u; } cv;
    cv.h = (_Float16)f;
    return cv.u;
}
__device__ __forceinline__ unsigned hdup(float f) {
    unsigned short u = f2h_us(f);
    return (unsigned)u | ((unsigned)u << 16);
}
__device__ __forceinline__ unsigned hfma2u(unsigned w, unsigned v, unsigned a) {
    union { unsigned u; __half2 h; } W, V, A, R;
    W.u = w; V.u = v; A.u = a;
    R.h = __hfma2(W.h, V.h, A.h);
    return R.u;
}
__device__ __forceinline__ unsigned hadd2u(unsigned a, unsigned b) {
    union { unsigned u; __half2 h; } A, B, R;
    A.u = a; B.u = b;
    R.h = __hadd2(A.h, B.h);
    return R.u;
}

#define GLOAD16(SRC, DST) \
    __builtin_amdgcn_global_load_lds( \
        (const __attribute__((address_space(1))) unsigned*)(SRC), \
        (__attribute__((address_space(3))) unsigned*)(DST), 16, 0, 0)

// ---------------------------------------------------------------------------
// prep_all: blocks 0..2047 x->bf16 (XCD-aligned); 2048..2099 Wt transpose;
// 2100 biasD+pad. Wt n-rows: 0-255 v_w | 256-399 qd_w | 400-471 qs_w |
// 472-543 qw_w | 544-575 zero | 576-831 out_w (f16; rest bf16).
// ---------------------------------------------------------------------------
__device__ __forceinline__ float wsrc(int k, int n,
    const float* v_w, const float* qd_w, const float* qs_w,
    const float* qw_w, const float* out_w)
{
    if (n < 256) return v_w[k * 256 + n];
    n -= 256;
    if (n < 144) return qd_w[k * 144 + n];
    n -= 144;
    if (n < 72)  return qs_w[k * 72 + n];
    n -= 72;
    if (n < 72)  return qw_w[k * 72 + n];
    n -= 72;
    if (n < 32)  return 0.f;
    return out_w[k * 256 + (n - 32)];
}

__global__ __launch_bounds__(256) void prep_all(
    const float* __restrict__ x, unsigned short* __restrict__ xb,
    const float* __restrict__ v_w, const float* __restrict__ qd_w,
    const float* __restrict__ qs_w, const float* __restrict__ qw_w,
    const float* __restrict__ out_w, const float* __restrict__ qd_b,
    const float* __restrict__ qw_b,
    unsigned short* __restrict__ Wt, float* __restrict__ biasD,
    unsigned short* __restrict__ vpad)
{
    __shared__ float t[64][65];
    const int bid = blockIdx.x;
    const int tid = threadIdx.x;

    if (bid < 2048) {
        const int bb = (bid >> 3) + (bid & 7) * 256;
        const size_t i = (size_t)bb * 256 + tid;
        const float4 v0 = *(const float4*)(x + i * 8);
        const float4 v1 = *(const float4*)(x + i * 8 + 4);
        uint4 pk;
        pk.x = f2bf(v0.x) | ((unsigned)f2bf(v0.y) << 16);
        pk.y = f2bf(v0.z) | ((unsigned)f2bf(v0.w) << 16);
        pk.z = f2bf(v1.x) | ((unsigned)f2bf(v1.y) << 16);
        pk.w = f2bf(v1.z) | ((unsigned)f2bf(v1.w) << 16);
        *(uint4*)(xb + i * 8) = pk;
        return;
    }
    if (bid == 2100) {
        for (int i = tid; i < 320; i += 256) {
            float bv = 0.f;
            if (i < 144)                  bv = qd_b[i];
            else if (i >= 216 && i < 288) bv = qw_b[i - 216];
            biasD[i] = bv;
        }
        for (int i = tid; i < 512; i += 256) vpad[i] = 0;
        return;
    }
    const int tile = bid - 2048;
    const int tn = tile % 13;
    const int tk = tile / 13;
    #pragma unroll
    for (int i = 0; i < 16; ++i) {
        const int idx = tid + i * 256;
        const int r = idx >> 6;
        const int c = idx & 63;
        t[r][c] = wsrc(tk * 64 + r, tn * 64 + c, v_w, qd_w, qs_w, qw_w, out_w);
    }
    __syncthreads();
    const bool asF16 = (tn >= 9);
    #pragma unroll
    for (int i = 0; i < 8; ++i) {
        const int idx = tid + i * 256;
        const int rn = idx >> 5;
        const int cc = idx & 31;
        unsigned pk;
        if (asF16)
            pk = (unsigned)f2h_us(t[cc * 2][rn]) | ((unsigned)f2h_us(t[cc * 2 + 1][rn]) << 16);
        else
            pk = (unsigned)f2bf(t[cc * 2][rn]) | ((unsigned)f2bf(t[cc * 2 + 1][rn]) << 16);
        ((unsigned*)(Wt + (size_t)(tn * 64 + rn) * 256 + tk * 64))[cc] = pk;
    }
}

// ---------------------------------------------------------------------------
// gemm_proj: [NPIX][256]bf16 @ Wt[j*64..][256]^T, j=0..8. XCD-remapped rows.
//   j<4  -> v_bf F16 GROUP-MAJOR [b][g][4096][32];  j>=4 -> proj f32 [NPIX][320]
// ---------------------------------------------------------------------------
__global__ __launch_bounds__(256) void gemm_proj(
    const unsigned short* __restrict__ A, const unsigned short* __restrict__ Wt,
    const float* __restrict__ v_b, const float* __restrict__ biasD,
    unsigned short* __restrict__ v_bf, float* __restrict__ proj)
{
    __shared__ unsigned short As[64 * 256];
    __shared__ unsigned short Bs[64 * 256];

    const int tid  = threadIdx.x;
    const int wid  = tid >> 6;
    const int lane = tid & 63;
    const int bx   = blockIdx.x;
    const int tile = (bx >> 3) + (bx & 7) * 32;
    const int row0 = tile * 64;
    const int j    = blockIdx.y;

    const unsigned short* Ab = A  + (size_t)row0 * 256;
    const unsigned short* Bb = Wt + (size_t)(j * 64) * 256;
    const int rl = lane >> 5;
    const int gl = lane & 31;

    #pragma unroll
    for (int it = 0; it < 8; ++it) {
        const int r   = wid * 16 + it * 2 + rl;
        const int gsw = gl ^ (r & 7);
        GLOAD16(Ab + r * 256 + gsw * 8, &As[(wid * 16 + it * 2) * 256]);
        GLOAD16(Bb + r * 256 + gsw * 8, &Bs[(wid * 16 + it * 2) * 256]);
    }
    asm volatile("s_waitcnt vmcnt(0)" ::: "memory");
    __syncthreads();

    f32x4 acc00 = {0,0,0,0}, acc01 = {0,0,0,0};
    f32x4 acc10 = {0,0,0,0}, acc11 = {0,0,0,0};

    const int wr = (wid >> 1) * 32;
    const int wc = (wid & 1) * 32;
    const int fr = lane & 15;
    const int fg = lane >> 4;

    const int ra0 = wr + fr, ra1 = ra0 + 16;
    const int rb0 = wc + fr, rb1 = rb0 + 16;
    const int sa  = ra0 & 7;
    const int sb  = rb0 & 7;

    #pragma unroll
    for (int t = 0; t < 8; ++t) {
        const int gran = t * 4 + fg;
        short8 a0 = *(const short8*)&As[ra0 * 256 + (gran ^ sa) * 8];
        short8 a1 = *(const short8*)&As[ra1 * 256 + (gran ^ sa) * 8];
        short8 b0 = *(const short8*)&Bs[rb0 * 256 + (gran ^ sb) * 8];
        short8 b1 = *(const short8*)&Bs[rb1 * 256 + (gran ^ sb) * 8];
        acc00 = __builtin_amdgcn_mfma_f32_16x16x32_bf16(a0, b0, acc00, 0, 0, 0);
        acc01 = __builtin_amdgcn_mfma_f32_16x16x32_bf16(a0, b1, acc01, 0, 0, 0);
        acc10 = __builtin_amdgcn_mfma_f32_16x16x32_bf16(a1, b0, acc10, 0, 0, 0);
        acc11 = __builtin_amdgcn_mfma_f32_16x16x32_bf16(a1, b1, acc11, 0, 0, 0);
    }

    if (j < 4) {
        const int colA = j * 64 + wc + fr;
        const int colB = colA + 16;
        const int gA = colA >> 5, cA = colA & 31;
        const int gB = colB >> 5, cB = colB & 31;
        const float biasA = v_b[colA];
        const float biasB = v_b[colB];
        #pragma unroll
        for (int jj = 0; jj < 4; ++jj) {
            const int r0a = row0 + wr + fg * 4 + jj;
            const int r1a = r0a + 16;
            const int b0i = r0a >> 12;
            const int hw0 = r0a & 4095, hw1 = r1a & 4095;
            v_bf[((size_t)(b0i * 8 + gA) * 4096 + hw0) * 32 + cA] = f2h_us(acc00[jj] + biasA);
            v_bf[((size_t)(b0i * 8 + gB) * 4096 + hw0) * 32 + cB] = f2h_us(acc01[jj] + biasB);
            v_bf[((size_t)(b0i * 8 + gA) * 4096 + hw1) * 32 + cA] = f2h_us(acc10[jj] + biasA);
            v_bf[((size_t)(b0i * 8 + gB) * 4096 + hw1) * 32 + cB] = f2h_us(acc11[jj] + biasB);
        }
    } else {
        const int colA = (j - 4) * 64 + wc + fr;
        const int colB = colA + 16;
        const float biasA = biasD[colA];
        const float biasB = biasD[colB];
        #pragma unroll
        for (int jj = 0; jj < 4; ++jj) {
            const int r0a = row0 + wr + fg * 4 + jj;
            const int r1a = r0a + 16;
            proj[(size_t)r0a * 320 + colA] = acc00[jj] + biasA;
            proj[(size_t)r0a * 320 + colB] = acc01[jj] + biasB;
            proj[(size_t)r1a * 320 + colA] = acc10[jj] + biasA;
            proj[(size_t)r1a * 320 + colB] = acc11[jj] + biasB;
        }
    }
}

// ---------------------------------------------------------------------------
// gemm_out: out[M][256] = mid[M][256](f16) @ WtO(f16)^T + out_b (f32 out).
// ---------------------------------------------------------------------------
__global__ __launch_bounds__(256) void gemm_out(
    const unsigned short* __restrict__ A, const unsigned short* __restrict__ WtO,
    const float* __restrict__ bias, float* __restrict__ Y)
{
    __shared__ unsigned short As[64 * 256];
    __shared__ unsigned short Bs[64 * 256];

    const int tid  = threadIdx.x;
    const int wid  = tid >> 6;
    const int lane = tid & 63;
    const int bx   = blockIdx.x;
    const int tile = (bx >> 3) + (bx & 7) * 32;
    const int row0 = tile * 64;
    const int col0 = blockIdx.y * 64;

    const unsigned short* Ab = A   + (size_t)row0 * 256;
    const unsigned short* Bb = WtO + (size_t)col0 * 256;
    const int rl = lane >> 5;
    const int gl = lane & 31;

    #pragma unroll
    for (int it = 0; it < 8; ++it) {
        const int r   = wid * 16 + it * 2 + rl;
        const int gsw = gl ^ (r & 7);
        GLOAD16(Ab + r * 256 + gsw * 8, &As[(wid * 16 + it * 2) * 256]);
        GLOAD16(Bb + r * 256 + gsw * 8, &Bs[(wid * 16 + it * 2) * 256]);
    }
    asm volatile("s_waitcnt vmcnt(0)" ::: "memory");
    __syncthreads();

    f32x4 acc00 = {0,0,0,0}, acc01 = {0,0,0,0};
    f32x4 acc10 = {0,0,0,0}, acc11 = {0,0,0,0};

    const int wr = (wid >> 1) * 32;
    const int wc = (wid & 1) * 32;
    const int fr = lane & 15;
    const int fg = lane >> 4;

    const int ra0 = wr + fr, ra1 = ra0 + 16;
    const int rb0 = wc + fr, rb1 = rb0 + 16;
    const int sa  = ra0 & 7;
    const int sb  = rb0 & 7;

    #pragma unroll
    for (int t = 0; t < 8; ++t) {
        const int gran = t * 4 + fg;
        half8 a0 = *(const half8*)&As[ra0 * 256 + (gran ^ sa) * 8];
        half8 a1 = *(const half8*)&As[ra1 * 256 + (gran ^ sa) * 8];
        half8 b0 = *(const half8*)&Bs[rb0 * 256 + (gran ^ sb) * 8];
        half8 b1 = *(const half8*)&Bs[rb1 * 256 + (gran ^ sb) * 8];
        acc00 = __builtin_amdgcn_mfma_f32_16x16x32_f16(a0, b0, acc00, 0, 0, 0);
        acc01 = __builtin_amdgcn_mfma_f32_16x16x32_f16(a0, b1, acc01, 0, 0, 0);
        acc10 = __builtin_amdgcn_mfma_f32_16x16x32_f16(a1, b0, acc10, 0, 0, 0);
        acc11 = __builtin_amdgcn_mfma_f32_16x16x32_f16(a1, b1, acc11, 0, 0, 0);
    }

    const int colA = col0 + wc + fr;
    const int colB = colA + 16;
    const float biasA = bias[colA];
    const float biasB = bias[colB];
    #pragma unroll
    for (int jj = 0; jj < 4; ++jj) {
        const int r0a = row0 + wr + fg * 4 + jj;
        const int r1a = r0a + 16;
        Y[(size_t)r0a * 256 + colA] = acc00[jj] + biasA;
        Y[(size_t)r0a * 256 + colB] = acc01[jj] + biasB;
        Y[(size_t)r1a * 256 + colA] = acc10[jj] + biasA;
        Y[(size_t)r1a * 256 + colB] = acc11[jj] + biasB;
    }
}

// ---------------------------------------------------------------------------
// Sampler v8: v7 + explicit 2-deep software pipeline in phase 2.
// Loads (offs/wpk LDS + 4 global gathers) for iteration k+1 are issued
// BEFORE the FMAs of iteration k, giving each gather ~1 iteration of
// latency cover (vs ~0 at the compiler's 40-VGPR schedule).
// ---------------------------------------------------------------------------
__global__ __launch_bounds__(256) void dcn_sample8(
    const unsigned short* __restrict__ vbuf,  // [4][8][4096][32] f16
    const float* __restrict__ proj,           // [NPIX][320]
    const float* __restrict__ prior,          // [K][2]
    const float* __restrict__ dscale,         // [G]
    unsigned short* __restrict__ mid)         // [NPIX][256] f16
{
    __shared__ int      offs[576 * 2];   //  4608 B
    __shared__ unsigned wpk [576 * 4];   //  9216 B

    const int tid = threadIdx.x;
    const int bid  = blockIdx.x;
    const int wg   = (bid & 7) * 256 + (bid >> 3);
    const int pix0 = wg * 8;

    for (int it = tid; it < 576; it += 256) {
        const int p   = it / 72;
        const int rem = it - p * 72;
        const int g   = rem / 9;
        const int k   = rem - g * 9;
        const int pix = pix0 + p;
        const int b   = pix >> 12;
        const int hw  = pix & 4095;
        const int h   = hw >> 6, w = hw & 63;

        const float* row = proj + (size_t)pix * 320;
        const float qdx = row[g * 18 + k * 2 + 0];
        const float qdy = row[g * 18 + k * 2 + 1];
        const float s   = row[144 + g * 9 + k] + dscale[g];
        const float wt  = row[216 + g * 9 + k];
        const float sig6 = 6.0f / (1.0f + __expf(-s));
        const float px = (float)w + (qdx + prior[k * 2 + 0]) * sig6;
        const float py = (float)h + (qdy + prior[k * 2 + 1]) * sig6;

        const float x0f = floorf(px), y0f = floorf(py);
        const int ix = (int)x0f, iy = (int)y0f;
        const float wx1 = px - x0f, wx0 = 1.f - wx1;
        const float wy1 = py - y0f, wy0 = 1.f - wy1;
        const int plane = (b * 8 + g) << 12;

        const bool vy0 = (iy >= 0) & (iy < 64);
        const bool vy1 = (iy >= -1) & (iy < 63);
        const bool vx0 = (ix >= 0) & (ix < 64);
        const bool vx1 = (ix >= -1) & (ix < 63);
        const float w00 = (vy0 & vx0) ? wt * wy0 * wx0 : 0.f;
        const float w10 = (vy1 & vx0) ? wt * wy1 * wx0 : 0.f;
        const float w01 = (vy0 & vx1) ? wt * wy0 * wx1 : 0.f;
        const float w11 = (vy1 & vx1) ? wt * wy1 * wx1 : 0.f;
        wpk[it * 4 + 0] = hdup(w00);
        wpk[it * 4 + 1] = hdup(w10);
        wpk[it * 4 + 2] = hdup(w01);
        wpk[it * 4 + 3] = hdup(w11);

        const int xs  = min(max(ix,     -1), 63);
        const int y0c = min(max(iy,      0), 63);
        const int y1c = min(max(iy + 1,  0), 63);
        offs[it * 2 + 0] = (plane + y0c * 64 + xs) * 64;   // BYTE offsets
        offs[it * 2 + 1] = (plane + y1c * 64 + xs) * 64;
    }
    __syncthreads();

    const int p4 = tid >> 6;
    const int g  = (tid >> 3) & 7;
    const int q  = tid & 7;
    const int xh = q >> 2;
    const int qb = q * 16;
    const char* vbb = (const char*)vbuf;

    unsigned aA0=0,aA1=0,aA2=0,aA3=0, aB0=0,aB1=0,aB2=0,aB3=0;
    unsigned bA0=0,bA1=0,bA2=0,bA3=0, bB0=0,bB1=0,bB2=0,bB3=0;
    const int item0a = p4 * 72 + g * 9;
    const int item0b = (p4 + 4) * 72 + g * 9;

    // ---- prologue: issue k=0 loads ----
    int2  o2a = *(const int2*)&offs[item0a * 2];
    int2  o2b = *(const int2*)&offs[item0b * 2];
    uint2 wpa = *(const uint2*)&wpk[item0a * 4 + xh * 2];
    uint2 wpb = *(const uint2*)&wpk[item0b * 4 + xh * 2];
    uint4 ra0 = *(const uint4*)(vbb + o2a.x + qb);
    uint4 ra1 = *(const uint4*)(vbb + o2a.y + qb);
    uint4 rb0 = *(const uint4*)(vbb + o2b.x + qb);
    uint4 rb1 = *(const uint4*)(vbb + o2b.y + qb);

    #pragma unroll
    for (int k = 0; k < 9; ++k) {
        const uint2 wpa_c = wpa, wpb_c = wpb;
        const uint4 ra0_c = ra0, ra1_c = ra1, rb0_c = rb0, rb1_c = rb1;

        if (k < 8) {   // issue k+1's loads before consuming k
            const int ita = item0a + k + 1;
            const int itb = item0b + k + 1;
            o2a = *(const int2*)&offs[ita * 2];
            o2b = *(const int2*)&offs[itb * 2];
            wpa = *(const uint2*)&wpk[ita * 4 + xh * 2];
            wpb = *(const uint2*)&wpk[itb * 4 + xh * 2];
            ra0 = *(const uint4*)(vbb + o2a.x + qb);
            ra1 = *(const uint4*)(vbb + o2a.y + qb);
            rb0 = *(const uint4*)(vbb + o2b.x + qb);
            rb1 = *(const uint4*)(vbb + o2b.y + qb);
        }

        aA0 = hfma2u(wpa_c.x, ra0_c.x, aA0);
        aA1 = hfma2u(wpa_c.x, ra0_c.y, aA1);
        aA2 = hfma2u(wpa_c.x, ra0_c.z, aA2);
        aA3 = hfma2u(wpa_c.x, ra0_c.w, aA3);
        aB0 = hfma2u(wpa_c.y, ra1_c.x, aB0);
        aB1 = hfma2u(wpa_c.y, ra1_c.y, aB1);
        aB2 = hfma2u(wpa_c.y, ra1_c.z, aB2);
        aB3 = hfma2u(wpa_c.y, ra1_c.w, aB3);
        bA0 = hfma2u(wpb_c.x, rb0_c.x, bA0);
        bA1 = hfma2u(wpb_c.x, rb0_c.y, bA1);
        bA2 = hfma2u(wpb_c.x, rb0_c.z, bA2);
        bA3 = hfma2u(wpb_c.x, rb0_c.w, bA3);
        bB0 = hfma2u(wpb_c.y, rb1_c.x, bB0);
        bB1 = hfma2u(wpb_c.y, rb1_c.y, bB1);
        bB2 = hfma2u(wpb_c.y, rb1_c.z, bB2);
        bB3 = hfma2u(wpb_c.y, rb1_c.w, bB3);
    }

    uint4 oA, oB;
    {
        unsigned c;
        c = hadd2u(aA0, aB0); c = hadd2u(c, (unsigned)__shfl_xor((int)c, 4)); oA.x = c;
        c = hadd2u(aA1, aB1); c = hadd2u(c, (unsigned)__shfl_xor((int)c, 4)); oA.y = c;
        c = hadd2u(aA2, aB2); c = hadd2u(c, (unsigned)__shfl_xor((int)c, 4)); oA.z = c;
        c = hadd2u(aA3, aB3); c = hadd2u(c, (unsigned)__shfl_xor((int)c, 4)); oA.w = c;
        c = hadd2u(bA0, bB0); c = hadd2u(c, (unsigned)__shfl_xor((int)c, 4)); oB.x = c;
        c = hadd2u(bA1, bB1); c = hadd2u(c, (unsigned)__shfl_xor((int)c, 4)); oB.y = c;
        c = hadd2u(bA2, bB2); c = hadd2u(c, (unsigned)__shfl_xor((int)c, 4)); oB.z = c;
        c = hadd2u(bA3, bB3); c = hadd2u(c, (unsigned)__shfl_xor((int)c, 4)); oB.w = c;
    }
    if (xh == 0) {
        const int cq8 = (q & 3) * 8;
        *(uint4*)(mid + (size_t)(pix0 + p4) * 256 + g * 32 + cq8) = oA;
        *(uint4*)(mid + (size_t)(pix0 + p4 + 4) * 256 + g * 32 + cq8) = oB;
    }
}

// ---------------------------------------------------------------------------
extern "C" void kernel_launch(void* const* d_in, const int* in_sizes, int n_in,
                              void* d_out, int out_size, void* d_ws, size_t ws_size,
                              hipStream_t stream)
{
    (void)in_sizes; (void)n_in; (void)out_size; (void)ws_size;

    const float* x      = (const float*)d_in[0];
    const float* v_w    = (const float*)d_in[1];
    const float* v_b    = (const float*)d_in[2];
    const float* qd_w   = (const float*)d_in[3];
    const float* qd_b   = (const float*)d_in[4];
    const float* qs_w   = (const float*)d_in[5];
    const float* qw_w   = (const float*)d_in[6];
    const float* qw_b   = (const float*)d_in[7];
    const float* out_w  = (const float*)d_in[8];
    const float* out_b  = (const float*)d_in[9];
    const float* prior  = (const float*)d_in[10];
    const float* dscale = (const float*)d_in[11];
    float* out = (float*)d_out;

    char* ws = (char*)d_ws;
    unsigned short* xb    = (unsigned short*)(ws);                    // 8 MB
    unsigned short* v_bf  = (unsigned short*)(ws + 8388608);          // 8 MB (f16)
    unsigned short* vpad  = (unsigned short*)(ws + 16777216);         // 1 KB guard
    float*          proj  = (float*)(ws + 16778240);                  // ~21 MB
    unsigned short* mid   = (unsigned short*)(ws + 37749760);         // 8 MB (f16)
    unsigned short* Wt    = (unsigned short*)(ws + 46138368);         // 416 KB
    float*          biasD = (float*)(ws + 46564352);                  // 1.25 KB

    prep_all<<<dim3(2101), dim3(256), 0, stream>>>(x, xb, v_w, qd_w, qs_w, qw_w,
                                                   out_w, qd_b, qw_b, Wt, biasD, vpad);

    gemm_proj<<<dim3(256, 9), dim3(256), 0, stream>>>(xb, Wt, v_b, biasD, v_bf, proj);

    dcn_sample8<<<dim3(NPIX / 8), dim3(256), 0, stream>>>(v_bf, proj, prior, dscale, mid);

    gemm_out<<<dim3(256, 4), dim3(256), 0, stream>>>(mid, Wt + 576 * 256, out_b, out);
}